// Round 3
// 417.881 us; speedup vs baseline: 1.0492x; 1.0492x over previous
//
#include <hip/hip_runtime.h>
#include <stdint.h>
#include <math.h>

// ---------------------------------------------------------------------------
// MultiHeadAttention: B=4, S=2048, D=1024, H=16, dk=64
// Raw-reshape head split: head (b,h) = rows [b*2048+h*128, +128) of the
// projected [8192][1024] matrix, reinterpreted as [2048][64].
// R5: R4 (32x32x16 MFMA attention) with the P path made layout-proof:
//   - P^T is written to LDS (per-wave [32 q][64 key] f16, 16B-granule XOR
//     swizzle) using only the HW-verified C/D layout, then the PV B-fragments
//     are read back with the SAME addressing convention as the V A-fragments.
//     Any unknown k-slot permutation is then shared by both PV operands and
//     cancels (dot-product invariance) — fixes R4's key mis-pairing.
//   - P pack is RNE (half2 bit_cast -> v_pack), not cvt_pkrtz (RTZ bias).
//   - everything else from R4 kept: 16 MFMA/tile, single-q-per-lane softmax
//     (one shfl_xor(32)/tile), defer-max THR=8, LDS-transpose epilogue,
//     async global_load_lds double-buffered K/V staging, one barrier/tile.
// ---------------------------------------------------------------------------

typedef __attribute__((ext_vector_type(8))) short short8;
typedef __attribute__((ext_vector_type(4))) float f32x4;
typedef __attribute__((ext_vector_type(16))) float f32x16;
typedef __attribute__((ext_vector_type(2))) unsigned int u32x2;
typedef __attribute__((ext_vector_type(4))) unsigned int u32x4;
typedef __attribute__((ext_vector_type(8))) _Float16 half8;
typedef __attribute__((ext_vector_type(2))) _Float16 half2v;

__device__ __forceinline__ unsigned short bf16rne(float f) {
  unsigned int u = __builtin_bit_cast(unsigned int, f);
  unsigned int r = u + 0x7FFFu + ((u >> 16) & 1u);
  return (unsigned short)(r >> 16);
}

// async global->LDS, 16B per lane. LDS dest must be wave-uniform base + lane*16.
__device__ __forceinline__ void gld_lds16(const void* g, void* l) {
  typedef __attribute__((address_space(3))) unsigned int lds_u32;
  typedef const __attribute__((address_space(1))) unsigned int glb_u32;
  __builtin_amdgcn_global_load_lds((glb_u32*)(uintptr_t)g,
                                   (lds_u32*)(unsigned int)(uintptr_t)l,
                                   16, 0, 0);
}

// pack two f32 -> one u32 of two f16 (RNE)
__device__ __forceinline__ unsigned pkrne(float a, float b) {
  half2v h;
  h[0] = (_Float16)a;
  h[1] = (_Float16)b;
  return __builtin_bit_cast(unsigned, h);
}

// ---------------------------------------------------------------------------
// fp32 -> bf16 convert for Q,K,V   (3 x 8192 x 1024)
// ---------------------------------------------------------------------------
__global__ void convert_x_kernel(const float* __restrict__ Q,
                                 const float* __restrict__ K,
                                 const float* __restrict__ V,
                                 unsigned short* __restrict__ Xb) {
  const int z = blockIdx.y;
  const float* src = (z == 0) ? Q : (z == 1) ? K : V;
  const size_t i0 = ((size_t)blockIdx.x * 256 + threadIdx.x) * 8;
  const f32x4 a = *(const f32x4*)(src + i0);
  const f32x4 c = *(const f32x4*)(src + i0 + 4);
  u32x4 o;
  o[0] = (unsigned)bf16rne(a[0]) | ((unsigned)bf16rne(a[1]) << 16);
  o[1] = (unsigned)bf16rne(a[2]) | ((unsigned)bf16rne(a[3]) << 16);
  o[2] = (unsigned)bf16rne(c[0]) | ((unsigned)bf16rne(c[1]) << 16);
  o[3] = (unsigned)bf16rne(c[2]) | ((unsigned)bf16rne(c[3]) << 16);
  *(u32x4*)(Xb + (size_t)z * 8388608 + i0) = o;
}

// ---------------------------------------------------------------------------
// W [K=1024][N=1024] fp32 -> Wt [N][K] bf16 (transposed so GEMMs are A*B^T)
// ---------------------------------------------------------------------------
__global__ void convert_w_kernel(const float* __restrict__ W0,
                                 const float* __restrict__ W1,
                                 const float* __restrict__ W2,
                                 const float* __restrict__ W3,
                                 unsigned short* __restrict__ Wt) {
  const int z = blockIdx.z;
  const float* W = (z == 0) ? W0 : (z == 1) ? W1 : (z == 2) ? W2 : W3;
  unsigned short* dst = Wt + (size_t)z * 1048576;
  __shared__ float tile[32][33];
  const int tx = threadIdx.x & 31, ty = threadIdx.x >> 5;
  const int k0 = blockIdx.x * 32, n0 = blockIdx.y * 32;
#pragma unroll
  for (int yy = 0; yy < 32; yy += 8)
    tile[ty + yy][tx] = W[(size_t)(k0 + ty + yy) * 1024 + n0 + tx];
  __syncthreads();
#pragma unroll
  for (int yy = 0; yy < 32; yy += 8)
    dst[(size_t)(n0 + ty + yy) * 1024 + k0 + tx] = bf16rne(tile[tx][ty + yy]);
}

// ---------------------------------------------------------------------------
// GEMM (m97 structure): C[z] = A[z][8192x1024] * Bt[z][1024x1024]^T
// ---------------------------------------------------------------------------
__global__ __launch_bounds__(256, 2) void gemm_bt_kernel(
    const unsigned short* __restrict__ A, const unsigned short* __restrict__ Bt,
    unsigned short* __restrict__ Cbf, float* __restrict__ Cf32, float scaleZ0) {
  constexpr int K = 1024, N = 1024;
  const int z = blockIdx.z;
  const unsigned short* Ab = A + (size_t)z * 8192 * 1024;
  const unsigned short* Bb = Bt + (size_t)z * 1024 * 1024;
  const int tid = threadIdx.x;
  const int lane = tid & 63;
  const int w = tid >> 6;
  const int l15 = lane & 15, quad = lane >> 4;
  const int rowBase = blockIdx.x * 128;
  const int colBase = blockIdx.y * 128;
  const int wrow = (w >> 1) * 64;
  const int wcol = (w & 1) * 64;
  __shared__ __align__(16) unsigned short As[128 * 32];
  __shared__ __align__(16) unsigned short Bs[128 * 32];

  const f32x4 z4 = {0.0f, 0.0f, 0.0f, 0.0f};
  f32x4 acc[4][4];
#pragma unroll
  for (int i = 0; i < 4; i++)
#pragma unroll
    for (int j = 0; j < 4; j++) acc[i][j] = z4;

  const int s0 = tid, s1 = tid + 256;
  const int rA0 = s0 >> 2, cA0 = (s0 & 3) * 8;
  const int rA1 = s1 >> 2, cA1 = (s1 & 3) * 8;

  for (int k0 = 0; k0 < K; k0 += 32) {
    gld_lds16(Ab + (size_t)(rowBase + rA0) * K + k0 + cA0, (void*)(As + s0 * 8));
    gld_lds16(Ab + (size_t)(rowBase + rA1) * K + k0 + cA1, (void*)(As + s1 * 8));
    gld_lds16(Bb + (size_t)(colBase + rA0) * K + k0 + cA0, (void*)(Bs + s0 * 8));
    gld_lds16(Bb + (size_t)(colBase + rA1) * K + k0 + cA1, (void*)(Bs + s1 * 8));
    __syncthreads();
    short8 af[4], bfr[4];
#pragma unroll
    for (int i = 0; i < 4; i++)
      af[i] = *(const short8*)(As + (wrow + i * 16 + l15) * 32 + quad * 8);
#pragma unroll
    for (int j = 0; j < 4; j++)
      bfr[j] = *(const short8*)(Bs + (wcol + j * 16 + l15) * 32 + quad * 8);
#pragma unroll
    for (int i = 0; i < 4; i++)
#pragma unroll
      for (int j = 0; j < 4; j++)
        acc[i][j] =
            __builtin_amdgcn_mfma_f32_16x16x32_bf16(af[i], bfr[j], acc[i][j], 0, 0, 0);
    __syncthreads();
  }

  const float sc = (z == 0) ? scaleZ0 : 1.0f;
#pragma unroll
  for (int i = 0; i < 4; i++) {
#pragma unroll
    for (int j = 0; j < 4; j++) {
#pragma unroll
      for (int r = 0; r < 4; r++) {
        const int row = rowBase + wrow + i * 16 + quad * 4 + r;
        const int col = colBase + wcol + j * 16 + l15;
        const float v = acc[i][j][r] * sc;
        if (Cbf != nullptr) {
          Cbf[(size_t)z * 8192 * 1024 + (size_t)row * N + col] = bf16rne(v);
        } else {
          Cf32[(size_t)row * N + col] = v;
        }
      }
    }
  }
}

// ---------------------------------------------------------------------------
// V transpose: lin_v head (b,h) [2048][64] bf16 -> Vt[bh][64][2048] f16.
// ---------------------------------------------------------------------------
__global__ void vtrans_kernel(const unsigned short* __restrict__ linv,
                              unsigned short* __restrict__ Vt) {
  const int st = blockIdx.x, bh = blockIdx.y;
  const unsigned short* vp = linv + (size_t)bh * 131072;
  __shared__ unsigned short tile[64 * 136];
  const int tid = threadIdx.x;
#pragma unroll
  for (int it = 0; it < 4; it++) {
    const int idx = it * 256 + tid;        // 0..1023
    const int s = idx >> 3, d0 = (idx & 7) * 8;
    const u32x4 vv = *(const u32x4*)(vp + (size_t)(st * 128 + s) * 64 + d0);
#pragma unroll
    for (int m = 0; m < 4; m++) {
      const unsigned lo = vv[m] & 0xffffu, hi = vv[m] >> 16;
      const float f0 = __builtin_bit_cast(float, lo << 16);
      const float f1 = __builtin_bit_cast(float, hi << 16);
      const _Float16 h0 = (_Float16)f0, h1 = (_Float16)f1;
      tile[(d0 + 2 * m) * 136 + s] = __builtin_bit_cast(unsigned short, h0);
      tile[(d0 + 2 * m + 1) * 136 + s] = __builtin_bit_cast(unsigned short, h1);
    }
  }
  __syncthreads();
#pragma unroll
  for (int it = 0; it < 4; it++) {
    const int idx = it * 256 + tid;
    const int d = idx >> 4, s0 = (idx & 15) * 8;
    const u32x4 o = *(const u32x4*)(tile + d * 136 + s0);
    *(u32x4*)(Vt + (size_t)bh * 131072 + (size_t)d * 2048 + st * 128 + s0) = o;
  }
}

// ---------------------------------------------------------------------------
// Flash attention, 32x32 MFMA path, async-LDS double-buffered.
// Grid (bh=64, qt=16); block 256 = 4 waves; wave w owns q-rows
// [qt*128+w*32, +32); lane's q = l&31.
// LDS: Ks [2][64 key][64 dk] 16KB + Vs [2][64 d][64 key] f16 16KB (both
// XOR-swizzled 16B segs) + per-wave P tile [32 q][64 key] f16 4KB x4 = 48KB.
// S^T = mfma_32x32x16_bf16(K, Q): C col = q = l&31, row = key =
// (r&3)+8*(r>>2)+4*(l>>5)  [HW-verified layout].
// P is packed (RNE) to f16, ds_written at its true key index, then re-read
// as B-fragments with the SAME addressing pattern used for V A-fragments —
// so any unknown k-slot permutation cancels between the PV operands.
// ---------------------------------------------------------------------------
__global__ __launch_bounds__(256, 3) void attn_kernel(
    const unsigned short* __restrict__ lin, const _Float16* __restrict__ Vt,
    unsigned short* __restrict__ ctxr) {
  const int bh = blockIdx.x;
  const int qt = blockIdx.y;
  const int b = bh >> 4, h = bh & 15;
  const int tid = threadIdx.x, lane = tid & 63, w = tid >> 6;
  const int l31 = lane & 31, hl = lane >> 5, x7 = l31 & 7;
  const size_t headOff = (size_t)(b * 2048 + h * 128) * 1024;
  const unsigned short* qp = lin + headOff;
  const unsigned short* kp = lin + 8388608 + headOff;
  const _Float16* vtp = Vt + (size_t)bh * 131072;

  __shared__ __align__(16) unsigned short smem[24576];  // 48 KB
  unsigned short(*Ks)[4096] = (unsigned short(*)[4096])smem;     // [2][4096]
  _Float16(*Vs)[4096] = (_Float16(*)[4096])(smem + 8192);        // [2][4096]
  _Float16* Pl = (_Float16*)(smem + 16384) + w * 2048;           // [32][64]

  // Staging geometry: waves 0,1 stage K (512 slots); waves 2,3 stage V.
  const int stageV = (w >= 2);
  const int wbase = (stageV ? (w - 2) : w) * 256 + lane;
  auto stage = [&](int bufn, int key0) {
#pragma unroll
    for (int i = 0; i < 4; i++) {
      const int slot = wbase + i * 64;
      const int row = slot >> 3;                 // key (K) or d (V)
      const int seg = (slot & 7) ^ (row & 7);    // un-swizzled segment
      if (!stageV) {
        gld_lds16(kp + (size_t)(key0 + row) * 64 + seg * 8,
                  (void*)(&Ks[bufn][slot * 8]));
      } else {
        gld_lds16(vtp + (size_t)row * 2048 + key0 + seg * 8,
                  (void*)(&Vs[bufn][slot * 8]));
      }
    }
  };

  // Q B-fragments (col = q = l31, k-window ks*16 + hl*8).
  const int qrow0 = qt * 128 + w * 32;
  short8 bq[4];
#pragma unroll
  for (int ks = 0; ks < 4; ks++)
    bq[ks] = *(const short8*)(qp + (size_t)(qrow0 + l31) * 64 + ks * 16 + hl * 8);

  f32x16 z16;
#pragma unroll
  for (int r = 0; r < 16; r++) z16[r] = 0.0f;
  f32x16 co[2] = {z16, z16};  // O^T: co[dt], d = dt*32+(r&3)+8*(r>>2)+4*hl
  float mrun = -INFINITY, lrun = 0.0f;

  stage(0, 0);
  __syncthreads();

  for (int kt = 0; kt < 32; kt++) {
    const int cur = kt & 1;
    if (kt < 31) stage(cur ^ 1, (kt + 1) * 64);

    // ---- S^T: 8x mfma_32x32x16_bf16 (2 key-groups x 4 dk-steps)
    f32x16 sacc[2] = {z16, z16};
    __builtin_amdgcn_s_setprio(1);
#pragma unroll
    for (int g = 0; g < 2; g++) {
#pragma unroll
      for (int ks = 0; ks < 4; ks++) {
        const int slot = (g * 32 + l31) * 8 + ((2 * ks + hl) ^ x7);
        const short8 kf = *(const short8*)(&Ks[cur][slot * 8]);
        sacc[g] =
            __builtin_amdgcn_mfma_f32_32x32x16_bf16(kf, bq[ks], sacc[g], 0, 0, 0);
      }
    }
    __builtin_amdgcn_s_setprio(0);

    // ---- V A-fragments (row = d = dt*32+l31, k-window 16*(2g+s) + hl*8):
    // 8x ds_read_b128, independent of sacc -> latency hides under softmax.
    half8 vf[2][2][2];  // [dt][g][s]
#pragma unroll
    for (int dt = 0; dt < 2; dt++)
#pragma unroll
      for (int g = 0; g < 2; g++)
#pragma unroll
        for (int s = 0; s < 2; s++) {
          const int slot = (dt * 32 + l31) * 8 + ((4 * g + 2 * s + hl) ^ x7);
          vf[dt][g][s] = *(const half8*)(&Vs[cur][slot * 8]);
        }

    // ---- online softmax (lane owns q = l31; keys split across wave halves)
    float pmax;
    {
      float tm[8];
#pragma unroll
      for (int r = 0; r < 8; r++)
        tm[r] = fmaxf(fmaxf(sacc[0][r], sacc[0][r + 8]),
                      fmaxf(sacc[1][r], sacc[1][r + 8]));
      const float a0 = fmaxf(fmaxf(tm[0], tm[1]), fmaxf(tm[2], tm[3]));
      const float a1 = fmaxf(fmaxf(tm[4], tm[5]), fmaxf(tm[6], tm[7]));
      pmax = fmaxf(a0, a1);
    }
    pmax = fmaxf(pmax, __shfl_xor(pmax, 32, 64));
    if (!__all(pmax - mrun <= 8.0f)) {  // defer-max: rescale only on real growth
      const float mnew = fmaxf(mrun, pmax);
      const float a = exp2f(mrun - mnew);
      mrun = mnew;
      lrun *= a;
#pragma unroll
      for (int r = 0; r < 16; r++) {
        co[0][r] *= a;
        co[1][r] *= a;
      }
    }
    float ls0 = 0.0f, ls1 = 0.0f, ls2 = 0.0f, ls3 = 0.0f;
#pragma unroll
    for (int g = 0; g < 2; g++) {
#pragma unroll
      for (int r = 0; r < 16; r += 4) {
        const float p0 = exp2f(sacc[g][r + 0] - mrun);
        const float p1 = exp2f(sacc[g][r + 1] - mrun);
        const float p2 = exp2f(sacc[g][r + 2] - mrun);
        const float p3 = exp2f(sacc[g][r + 3] - mrun);
        sacc[g][r + 0] = p0;
        sacc[g][r + 1] = p1;
        sacc[g][r + 2] = p2;
        sacc[g][r + 3] = p3;
        ls0 += p0;
        ls1 += p1;
        ls2 += p2;
        ls3 += p3;
      }
    }
    lrun += (ls0 + ls1) + (ls2 + ls3);

    // ---- P -> LDS at true key index (C-layout: key_in_grp = 8rg+4hl+t),
    // [32 q][64 key] f16, 16B-seg XOR swizzle (seg ^ (q&7)).
#pragma unroll
    for (int g = 0; g < 2; g++) {
#pragma unroll
      for (int rg = 0; rg < 4; rg++) {
        u32x2 pw;
        pw[0] = pkrne(sacc[g][4 * rg + 0], sacc[g][4 * rg + 1]);
        pw[1] = pkrne(sacc[g][4 * rg + 2], sacc[g][4 * rg + 3]);
        *(u32x2*)(Pl + l31 * 64 + (((4 * g + rg) ^ x7) * 8) + hl * 4) = pw;
      }
    }
    // ---- P B-fragments: same addressing convention as V A-fragments.
    half8 pf[2][2];  // [g][s]
#pragma unroll
    for (int g = 0; g < 2; g++)
#pragma unroll
      for (int s = 0; s < 2; s++)
        pf[g][s] =
            *(const half8*)(Pl + l31 * 64 + (((4 * g + 2 * s + hl) ^ x7) * 8));

    // ---- O^T += V^T P^T : 8x mfma_32x32x16_f16
    __builtin_amdgcn_s_setprio(1);
#pragma unroll
    for (int dt = 0; dt < 2; dt++)
#pragma unroll
      for (int g = 0; g < 2; g++)
#pragma unroll
        for (int s = 0; s < 2; s++)
          co[dt] = __builtin_amdgcn_mfma_f32_32x32x16_f16(vf[dt][g][s], pf[g][s],
                                                          co[dt], 0, 0, 0);
    __builtin_amdgcn_s_setprio(0);
    __syncthreads();  // drains stage loads; separates buffer reuse
  }

  // ---- epilogue: normalize, transpose via LDS, coalesced b128 stores.
  lrun += __shfl_xor(lrun, 32, 64);
  const float inv = 1.0f / lrun;
  unsigned short* Cw = smem + w * 2304;  // per-wave 32 rows x stride 72
#pragma unroll
  for (int dt = 0; dt < 2; dt++) {
#pragma unroll
    for (int r = 0; r < 16; r++) {
      const int d = dt * 32 + (r & 3) + 8 * (r >> 2) + 4 * hl;
      Cw[l31 * 72 + d] = bf16rne(co[dt][r] * inv);
    }
  }
  __syncthreads();
#pragma unroll
  for (int it = 0; it < 4; it++) {
    const int q = it * 8 + (lane >> 3);
    const int seg = lane & 7;
    const u32x4 o = *(const u32x4*)(Cw + q * 72 + seg * 8);
    *(u32x4*)(ctxr + (size_t)(b * 2048 + qrow0 + q) * 1024 + h * 64 + seg * 8) = o;
  }
}

// ---------------------------------------------------------------------------
extern "C" void kernel_launch(void* const* d_in, const int* in_sizes, int n_in,
                              void* d_out, int out_size, void* d_ws, size_t ws_size,
                              hipStream_t stream) {
  const float* Q = (const float*)d_in[0];
  const float* K = (const float*)d_in[1];
  const float* V = (const float*)d_in[2];
  const float* WQ = (const float*)d_in[3];
  const float* WK = (const float*)d_in[4];
  const float* WV = (const float*)d_in[5];
  const float* Wfc = (const float*)d_in[6];
  float* out = (float*)d_out;

  unsigned short* ws = (unsigned short*)d_ws;
  // ws layout (ushort units):
  //   Xb   @ 0         : 3*8388608  (bf16 Q,K,V)      [dead after projections]
  //   ctxr @ 0         : 8388608    (bf16 ctx)        [overlays Xb]
  //   Vt   @ 8388608   : 8388608    (f16 V^T)         [overlays Xb]
  //   Wt   @ 25165824  : 4*1048576  (bf16 W^T: q,k,v,fc)
  //   lin  @ 29360128  : 3*8388608  (bf16 projections)
  unsigned short* Xb = ws;
  unsigned short* ctxr = ws;
  unsigned short* Vt = ws + 8388608;
  unsigned short* Wt = ws + 25165824;
  unsigned short* lin = ws + 29360128;

  convert_x_kernel<<<dim3(4096, 3), 256, 0, stream>>>(Q, K, V, Xb);
  convert_w_kernel<<<dim3(32, 32, 4), 256, 0, stream>>>(WQ, WK, WV, Wfc, Wt);
  const float qscale = 0.125f * 1.4426950408889634f;  // 1/sqrt(dk) * log2(e)
  gemm_bt_kernel<<<dim3(64, 8, 3), 256, 0, stream>>>(Xb, Wt, lin, nullptr, qscale);
  vtrans_kernel<<<dim3(16, 64), 256, 0, stream>>>(lin + 16777216, Vt);
  attn_kernel<<<dim3(64, 16), 256, 0, stream>>>(lin, (const _Float16*)Vt, ctxr);
  gemm_bt_kernel<<<dim3(64, 8, 1), 256, 0, stream>>>(ctxr, Wt + 3 * 1048576, nullptr,
                                                     out, 1.0f);
}